// Round 4
// baseline (277.327 us; speedup 1.0000x reference)
//
#include <hip/hip_runtime.h>
#include <hip/hip_bf16.h>
#include <math.h>

#define BB 4096
#define DD 256
#define GG 100
#define GAMMA_C 0.8f
#define RHO_C 8.0f
#define ALPHA_C 0.5f
#define EPS_C 1e-14f
#define NSR 64    // row stripes (64-col tiles)
#define NSC 32    // col stripes (one per 128-row block; waves pre-combined)

typedef __bf16 bf16x8 __attribute__((ext_vector_type(8)));
typedef float f32x16 __attribute__((ext_vector_type(16)));

// 32-row fragment-swizzled layout for mfma_32x32x16: element (r,k) ->
//   row_blk=r>>5 (stride 8192), step=k>>4 (stride 512),
//   lane=((k>>3)&1)*32 + (r&31) (stride 8), pos=k&7. Packs exactly.
__device__ inline int swzLoc(int r31, int k) {   // offset within 8192-elem block
    return ((k >> 4) << 9) | (((((k >> 3) & 1) << 5) | r31) << 3) | (k & 7);
}

__device__ inline float blockReduceSum(float v, float* lds) {
    for (int o = 32; o > 0; o >>= 1) v += __shfl_down(v, o);
    int lane = threadIdx.x & 63, wid = threadIdx.x >> 6;
    if (lane == 0) lds[wid] = v;
    __syncthreads();
    if (threadIdx.x == 0) {
        float r = lds[0];
        int nw = blockDim.x >> 6;
        for (int w = 1; w < nw; w++) r += lds[w];
        lds[0] = r;
    }
    __syncthreads();
    float r = lds[0];
    __syncthreads();
    return r;
}

// ---------------- 1) normalize + hi/lo split, LDS-staged swizzled stores ----
__global__ void __launch_bounds__(256) norm_kernel(const float* __restrict__ zis,
                            const float* __restrict__ zjs,
                            ushort* __restrict__ zhi, ushort* __restrict__ zlo,
                            ushort* __restrict__ whi, ushort* __restrict__ wlo,
                            float* __restrict__ diag, float* __restrict__ acc) {
    __shared__ ushort st[4][8192];   // 64 KB staging (zhi,zlo,whi,wlo)
    int rb = blockIdx.x;             // 0..127
    int wv = threadIdx.x >> 6, lane = threadIdx.x & 63;
    if (rb == 0) { acc[threadIdx.x] = 0.f; acc[threadIdx.x + 256] = 0.f; }
    for (int rr = 0; rr < 8; rr++) {
        int r = rb * 32 + wv * 8 + rr;
        float4 zv = *(const float4*)&zis[r * DD + lane * 4];
        float4 wv4 = *(const float4*)&zjs[r * DD + lane * 4];
        float sz = zv.x * zv.x + zv.y * zv.y + zv.z * zv.z + zv.w * zv.w;
        float sw = wv4.x * wv4.x + wv4.y * wv4.y + wv4.z * wv4.z + wv4.w * wv4.w;
        float dt = zv.x * wv4.x + zv.y * wv4.y + zv.z * wv4.z + zv.w * wv4.w;
        for (int mask = 1; mask <= 32; mask <<= 1) {
            sz += __shfl_xor(sz, mask);
            sw += __shfl_xor(sw, mask);
            dt += __shfl_xor(dt, mask);
        }
        float iz = 1.0f / fmaxf(sqrtf(sz), 1e-12f);
        float iw = 1.0f / fmaxf(sqrtf(sw), 1e-12f);
        if (lane == 0) diag[r] = dt * iz * iw;
        float nz[4] = {zv.x * iz, zv.y * iz, zv.z * iz, zv.w * iz};
        float nw[4] = {wv4.x * iw, wv4.y * iw, wv4.z * iw, wv4.w * iw};
        int r31 = wv * 8 + rr;
        for (int e = 0; e < 4; e++) {
            int k = lane * 4 + e;
            int li = swzLoc(r31, k);
            __hip_bfloat16 hz = __float2bfloat16(nz[e]);
            __hip_bfloat16 lz = __float2bfloat16(nz[e] - __bfloat162float(hz));
            __hip_bfloat16 hw = __float2bfloat16(nw[e]);
            __hip_bfloat16 lw = __float2bfloat16(nw[e] - __bfloat162float(hw));
            st[0][li] = *(ushort*)&hz;
            st[1][li] = *(ushort*)&lz;
            st[2][li] = *(ushort*)&hw;
            st[3][li] = *(ushort*)&lw;
        }
    }
    __syncthreads();
    size_t base = (size_t)rb * 8192;
    ushort* dsts[4] = {zhi + base, zlo + base, whi + base, wlo + base};
    for (int a = 0; a < 4; a++) {
        uint4* d = (uint4*)dsts[a];
        const uint4* s = (const uint4*)st[a];
        for (int it = 0; it < 4; it++) {
            int idx = it * 256 + threadIdx.x;
            d[idx] = s[idx];
        }
    }
}

// ---------------- 2) fused tile: 128x64 block, 32x32x16 MFMA ---------------
// R3 structure, occupancy-tuned: the 32x65 per-wave transpose buffer is
// halved to 16 rows x 2 rounds (LDS 37.9 -> 21.2 KB) and launch_bounds
// raised to 6 waves/EU (6 blocks/CU, +50% TLP for load-latency hiding).
// Each wave reads ONLY its own tr16[wv]: wave-internal lgkmcnt ordering
// makes the dump->read->redump sequence barrier-free (compiler-inserted
// waits). All tr16 reads/writes are exactly 2-way bank-aliased = free.
__global__ void __launch_bounds__(256, 6) fused_tile(const ushort* __restrict__ Ahi,
        const ushort* __restrict__ Alo, const ushort* __restrict__ Bhi,
        const ushort* __restrict__ Blo, const float* __restrict__ diag,
        const float* __restrict__ tausI, const float* __restrict__ tausT,
        const int* __restrict__ ids,
        float* __restrict__ pmR, float* __restrict__ pgR, float* __restrict__ pwR,
        float* __restrict__ pmC, float* __restrict__ pgC, float* __restrict__ pwC) {
    __shared__ float rDiag[128], rITau[128];
    __shared__ float cDiag[64], cITau[64];
    __shared__ float cmS[4][64], cgS[4][64], cwS[4][64];  // wave col partials
    __shared__ float tr16[4][16 * 65];  // per-wave 16x64 transpose, stride 65

    int lane = threadIdx.x & 63;
    int wv = threadIdx.x >> 6;
    int bm = blockIdx.y * 128, bn = blockIdx.x * 64;
    int h = lane >> 5, cl = lane & 31;

    if (threadIdx.x < 128) {
        int r = bm + threadIdx.x;
        rDiag[threadIdx.x] = diag[r];
        rITau[threadIdx.x] = 1.0f / tausI[ids[r]];
    } else if (threadIdx.x < 192) {
        int c = bn + threadIdx.x - 128;
        cDiag[threadIdx.x - 128] = diag[c];
        cITau[threadIdx.x - 128] = 1.0f / tausT[ids[c]];
    }

    int aBase = (blockIdx.y * 4 + wv) * 8192;
    int b0 = (blockIdx.x * 2) * 8192;
    int b1 = b0 + 8192;
    int lofs = lane * 8;

    f32x16 acc[2] = {};   // sim: row(reg)=bm+wv*32+idx, col(lane)=bn+u*32+cl
#pragma unroll
    for (int s = 0; s < 16; s++) {
        int so = s * 512 + lofs;
        bf16x8 ah  = *(const bf16x8*)&Ahi[aBase + so];
        bf16x8 al  = *(const bf16x8*)&Alo[aBase + so];
        bf16x8 bh0 = *(const bf16x8*)&Bhi[b0 + so];
        bf16x8 bl0 = *(const bf16x8*)&Blo[b0 + so];
        bf16x8 bh1 = *(const bf16x8*)&Bhi[b1 + so];
        bf16x8 bl1 = *(const bf16x8*)&Blo[b1 + so];
        acc[0] = __builtin_amdgcn_mfma_f32_32x32x16_bf16(ah, bh0, acc[0], 0, 0, 0);
        acc[1] = __builtin_amdgcn_mfma_f32_32x32x16_bf16(ah, bh1, acc[1], 0, 0, 0);
        acc[0] = __builtin_amdgcn_mfma_f32_32x32x16_bf16(ah, bl0, acc[0], 0, 0, 0);
        acc[1] = __builtin_amdgcn_mfma_f32_32x32x16_bf16(ah, bl1, acc[1], 0, 0, 0);
        acc[0] = __builtin_amdgcn_mfma_f32_32x32x16_bf16(al, bh0, acc[0], 0, 0, 0);
        acc[1] = __builtin_amdgcn_mfma_f32_32x32x16_bf16(al, bh1, acc[1], 0, 0, 0);
    }

    // ---- col side (per wave: 64 cols x its 32 rows), in-register ----
    // C/D layout [m74/m101]: col=lane&31, row=(reg&3)+8*(reg>>2)+4*(lane>>5)
    __syncthreads();  // params visible
    float cd2[2], cit2[2], cbloc[2], cg[2] = {}, cw[2] = {};
#pragma unroll
    for (int u = 0; u < 2; u++) {
        int clc = u * 32 + cl;
        cd2[u] = cDiag[clc];
        cit2[u] = cITau[clc];
        float m = -INFINITY;
#pragma unroll
        for (int reg = 0; reg < 16; reg++) m = fmaxf(m, acc[u][reg]);
        m = fmaxf(m, __shfl_xor(m, 32));
        cbloc[u] = (m - cd2[u]) * cit2[u];
    }
#pragma unroll
    for (int u = 0; u < 2; u++) {
        int gc = bn + u * 32 + cl;
#pragma unroll
        for (int reg = 0; reg < 16; reg++) {
            int gr = bm + wv * 32 + (reg & 3) + 4 * h + 8 * (reg >> 2);
            float v = acc[u][reg];
            bool off = gr != gc;
            float dvT = v - cd2[u];
            float eT = off ? __expf(dvT * cit2[u] - cbloc[u]) : 0.f;
            cg[u] += eT;
            cw[u] += eT * dvT;
        }
    }
#pragma unroll
    for (int u = 0; u < 2; u++) {
        cg[u] += __shfl_xor(cg[u], 32);
        cw[u] += __shfl_xor(cw[u], 32);
        if (h == 0) {
            cmS[wv][u * 32 + cl] = cbloc[u];
            cgS[wv][u * 32 + cl] = cg[u];
            cwS[wv][u * 32 + cl] = cw[u];
        }
    }
    __syncthreads();  // cmS visible for col-combine

    // flash-combine 4 waves -> 1 col stripe per block (NSC=32)
    if (threadIdx.x < 64) {
        int c = threadIdx.x;
        float m = fmaxf(fmaxf(cmS[0][c], cmS[1][c]), fmaxf(cmS[2][c], cmS[3][c]));
        float g = 0.f, w = 0.f;
        for (int wq = 0; wq < 4; wq++) {
            float f = __expf(cmS[wq][c] - m);
            g += cgS[wq][c] * f;
            w += cwS[wq][c] * f;
        }
        size_t o = (size_t)blockIdx.y * BB + bn + c;
        pmC[o] = m;
        pgC[o] = g;
        pwC[o] = w;
    }

    // ---- row side: 2 rounds of 16 rows via per-wave tr16 (no barriers:
    //      each wave only touches tr16[wv]; lgkmcnt orders dump/read) ----
    int stripeR = blockIdx.x;
#pragma unroll
    for (int hf = 0; hf < 2; hf++) {
        // dump regs hf*8..hf*8+7 (rows hf*16..hf*16+15 of this wave's tile)
#pragma unroll
        for (int u = 0; u < 2; u++)
#pragma unroll
            for (int rr = 0; rr < 8; rr++) {
                int r = (rr & 3) + 4 * h + 8 * (rr >> 2);   // 0..15
                tr16[wv][r * 65 + u * 32 + cl] = acc[u][hf * 8 + rr];
            }
        // lane (cl,h) -> row = cl&15, col-quarter q = (h<<1)|(cl>>4)
        int row = cl & 15;
        int q = (h << 1) | (cl >> 4);
        int rl = wv * 32 + hf * 16 + row;
        int grow = bm + rl;
        float rd = rDiag[rl];
        float rit = rITau[rl];
        float vv[16];
#pragma unroll
        for (int j = 0; j < 16; j++) vv[j] = tr16[wv][row * 65 + q * 16 + j];
        float m = -INFINITY;
#pragma unroll
        for (int j = 0; j < 16; j++) m = fmaxf(m, vv[j]);
        m = fmaxf(m, __shfl_xor(m, 16));
        m = fmaxf(m, __shfl_xor(m, 32));
        float bloc = (m - rd) * rit;
        float rg = 0.f, rw = 0.f;
#pragma unroll
        for (int j = 0; j < 16; j++) {
            int gc = bn + q * 16 + j;
            float dv = vv[j] - rd;
            float e = (grow != gc) ? __expf(dv * rit - bloc) : 0.f;
            rg += e;
            rw += e * dv;
        }
        rg += __shfl_xor(rg, 16);
        rg += __shfl_xor(rg, 32);
        rw += __shfl_xor(rw, 16);
        rw += __shfl_xor(rw, 32);
        if ((lane & 48) == 0) {   // h==0 && cl<16: one writer per row
            size_t o = (size_t)stripeR * BB + grow;
            pmR[o] = bloc;
            pgR[o] = rg;
            pwR[o] = rw;
        }
    }
}

// acc layout: [0]=lossI [1]=lossT [2..101]=gradI [102..201]=cntI
//             [202..301]=gradT [302..401]=cntT  [408]=completion counter(int)
// ---------------- 3) finalize: 256 blocks (2 sides x 128 chunks of 32 i) ---
// 256 threads = 32 i x 8 stripe-groups; online flash reduction per thread,
// LDS-combine across groups. 256 blocks = full CU coverage (was 128).
__global__ void __launch_bounds__(256) fin_kernel(
        const float* __restrict__ pmR, const float* __restrict__ pgR,
        const float* __restrict__ pwR, const float* __restrict__ pmC,
        const float* __restrict__ pgC, const float* __restrict__ pwC,
        const float* __restrict__ sI, const float* __restrict__ bI,
        const float* __restrict__ tausI, const int* __restrict__ gInfI,
        const float* __restrict__ pI,
        const float* __restrict__ sT, const float* __restrict__ bT,
        const float* __restrict__ tausT, const int* __restrict__ gInfT,
        const float* __restrict__ pT,
        const int* __restrict__ ids, float* __restrict__ acc,
        const float* __restrict__ zI, const float* __restrict__ zT,
        float* __restrict__ out) {
    __shared__ float lds[8];
    __shared__ float binF[GG], binC[GG];
    __shared__ float mS[8][32], gS[8][32], wS[8][32];
    __shared__ int lastFlag;
    if (threadIdx.x < GG) { binF[threadIdx.x] = 0.f; binC[threadIdx.x] = 0.f; }
    int side = blockIdx.x >> 7;
    int chunk = blockIdx.x & 127;
    int il = threadIdx.x & 31;
    int sg = threadIdx.x >> 5;
    int i = chunk * 32 + il;
    int ns = side ? NSC : NSR;
    const float* pm = side ? pmC : pmR;
    const float* pg = side ? pgC : pgR;
    const float* pw = side ? pwC : pwR;
    const float* sS = side ? sT : sI;
    const float* bS = side ? bT : bI;
    const float* taus = side ? tausT : tausI;
    const int* ginfo = side ? gInfT : gInfI;
    const float* pP = side ? pT : pI;

    // online flash over this group's stripes
    float m = -INFINITY, g = 0.f, w = 0.f;
    for (int s = sg; s < ns; s += 8) {
        float pms = pm[(size_t)s * BB + i];
        float pgs = pg[(size_t)s * BB + i];
        float pws = pw[(size_t)s * BB + i];
        float mn = fmaxf(m, pms);
        float fo = __expf(m - mn);
        float fs = __expf(pms - mn);
        g = g * fo + pgs * fs;
        w = w * fo + pws * fs;
        m = mn;
    }
    mS[sg][il] = m;
    gS[sg][il] = g;
    wS[sg][il] = w;
    __syncthreads();

    float loss = 0.f;
    if (sg == 0) {
        int id = ids[i];
        float oldb = bS[id];
        float mm = mS[0][il];
        for (int q = 1; q < 8; q++) mm = fmaxf(mm, mS[q][il]);
        float bfin = fmaxf(mm, oldb);
        float gg2 = 0.f, ww2 = 0.f;
        for (int q = 0; q < 8; q++) {
            float f = __expf(mS[q][il] - bfin);
            gg2 += gS[q][il] * f;
            ww2 += wS[q][il] * f;
        }
        float tau = taus[id];
        float snew = (1.f - GAMMA_C) * sS[id] * expf(oldb - bfin) + GAMMA_C * gg2;
        float sc = fmaxf(snew, EPS_C);
        int gid = ginfo[id];
        float gw = (float)GG * pP[gid];
        loss = gw * ww2 / sc;
        float F = tau * (logf(sc) + bfin + RHO_C);
        atomicAdd(&binF[gid], F);
        atomicAdd(&binC[gid], 1.0f);
    }
    float lsum = blockReduceSum(loss, lds);
    if (threadIdx.x == 0) atomicAdd(&acc[side], lsum);
    __syncthreads();
    if (threadIdx.x < GG) {
        atomicAdd(&acc[2 + side * 200 + threadIdx.x], binF[threadIdx.x]);
        atomicAdd(&acc[102 + side * 200 + threadIdx.x], binC[threadIdx.x]);
    }

    // ---- completion counter: last of 256 blocks runs the p-update phase ----
    __threadfence();
    if (threadIdx.x == 0) {
        int old = atomicAdd((int*)&acc[408], 1);
        lastFlag = (old == 255);
    }
    __syncthreads();
    if (!lastFlag) return;

    int gg = threadIdx.x;
    float npI = 0.f, npT = 0.f;
    if (gg < GG) {
        float cI = __hip_atomic_load(&acc[102 + gg], __ATOMIC_RELAXED, __HIP_MEMORY_SCOPE_AGENT);
        float fI = __hip_atomic_load(&acc[2 + gg], __ATOMIC_RELAXED, __HIP_MEMORY_SCOPE_AGENT);
        float gpI = fI / fmaxf(cI, 1.f);
        float zi = (1.f - GAMMA_C) * zI[gg] + GAMMA_C * gpI;
        float ghpI = -logf(pI[gg] + EPS_C) - 1.f;
        float ti = fminf(fmaxf(zi + ghpI, -5.f), 5.f);
        npI = pI[gg] * expf(0.02f * ti);

        float cT = __hip_atomic_load(&acc[302 + gg], __ATOMIC_RELAXED, __HIP_MEMORY_SCOPE_AGENT);
        float fT = __hip_atomic_load(&acc[202 + gg], __ATOMIC_RELAXED, __HIP_MEMORY_SCOPE_AGENT);
        float gpT = fT / fmaxf(cT, 1.f);
        float zt = (1.f - GAMMA_C) * zT[gg] + GAMMA_C * gpT;
        float ghpT = -logf(pT[gg] + EPS_C) - 1.f;
        float tt = fminf(fmaxf(zt + ghpT, -5.f), 5.f);
        npT = pT[gg] * expf(0.02f * tt);
    }
    float sumI = blockReduceSum(npI, lds);
    float sumT = blockReduceSum(npT, lds);
    if (gg < GG) {
        out[1 + gg] = npI / sumI;
        out[101 + gg] = npT / sumT;
    }
    if (gg == 0) {
        float lI = __hip_atomic_load(&acc[0], __ATOMIC_RELAXED, __HIP_MEMORY_SCOPE_AGENT);
        float lT = __hip_atomic_load(&acc[1], __ATOMIC_RELAXED, __HIP_MEMORY_SCOPE_AGENT);
        out[0] = ALPHA_C * (lI / (float)BB) + (1.f - ALPHA_C) * (lT / (float)BB);
    }
}

extern "C" void kernel_launch(void* const* d_in, const int* in_sizes, int n_in,
                              void* d_out, int out_size, void* d_ws, size_t ws_size,
                              hipStream_t stream) {
    const float* zis   = (const float*)d_in[0];
    const float* zjs   = (const float*)d_in[1];
    const float* s_I   = (const float*)d_in[2];
    const float* s_T   = (const float*)d_in[3];
    const float* b_I   = (const float*)d_in[4];
    const float* b_T   = (const float*)d_in[5];
    const float* z_I   = (const float*)d_in[6];
    const float* z_T   = (const float*)d_in[7];
    const float* p_I   = (const float*)d_in[8];
    const float* p_T   = (const float*)d_in[9];
    const float* tausI = (const float*)d_in[10];
    const float* tausT = (const float*)d_in[11];
    const int*   ids   = (const int*)d_in[12];
    const int*   gInfI = (const int*)d_in[13];
    const int*   gInfT = (const int*)d_in[14];
    float* out = (float*)d_out;

    char* ws = (char*)d_ws;
    ushort* zhi = (ushort*)ws;                         // BB*DD u16 each
    ushort* zlo = zhi + (size_t)BB * DD;
    ushort* whi = zlo + (size_t)BB * DD;
    ushort* wlo = whi + (size_t)BB * DD;
    float* acc  = (float*)(wlo + (size_t)BB * DD);     // 512
    float* diag = acc + 512;                           // BB
    float* pmR  = diag + BB;                           // NSR*BB each
    float* pgR  = pmR + (size_t)NSR * BB;
    float* pwR  = pgR + (size_t)NSR * BB;
    float* pmC  = pwR + (size_t)NSR * BB;              // NSC*BB each
    float* pgC  = pmC + (size_t)NSC * BB;
    float* pwC  = pgC + (size_t)NSC * BB;

    norm_kernel<<<128, 256, 0, stream>>>(zis, zjs, zhi, zlo, whi, wlo, diag, acc);
    fused_tile<<<dim3(64, 32), 256, 0, stream>>>(zhi, zlo, whi, wlo, diag,
            tausI, tausT, ids, pmR, pgR, pwR, pmC, pgC, pwC);
    fin_kernel<<<256, 256, 0, stream>>>(pmR, pgR, pwR, pmC, pgC, pwC,
            s_I, b_I, tausI, gInfI, p_I, s_T, b_T, tausT, gInfT, p_T, ids, acc,
            z_I, z_T, out);
}

// Round 5
// 272.783 us; speedup vs baseline: 1.0167x; 1.0167x over previous
//
#include <hip/hip_runtime.h>
#include <hip/hip_bf16.h>
#include <math.h>

#define BB 4096
#define DD 256
#define GG 100
#define GAMMA_C 0.8f
#define RHO_C 8.0f
#define ALPHA_C 0.5f
#define EPS_C 1e-14f
#define NSR 64    // row stripes (64-col tiles)
#define NSC 32    // col stripes (one per 128-row block; waves pre-combined)

typedef __bf16 bf16x8 __attribute__((ext_vector_type(8)));
typedef float f32x16 __attribute__((ext_vector_type(16)));

// 32-row fragment-swizzled layout for mfma_32x32x16: element (r,k) ->
//   row_blk=r>>5 (stride 8192), step=k>>4 (stride 512),
//   lane=((k>>3)&1)*32 + (r&31) (stride 8), pos=k&7. Packs exactly.
__device__ inline int swzLoc(int r31, int k) {   // offset within 8192-elem block
    return ((k >> 4) << 9) | (((((k >> 3) & 1) << 5) | r31) << 3) | (k & 7);
}

__device__ inline float blockReduceSum(float v, float* lds) {
    for (int o = 32; o > 0; o >>= 1) v += __shfl_down(v, o);
    int lane = threadIdx.x & 63, wid = threadIdx.x >> 6;
    if (lane == 0) lds[wid] = v;
    __syncthreads();
    if (threadIdx.x == 0) {
        float r = lds[0];
        int nw = blockDim.x >> 6;
        for (int w = 1; w < nw; w++) r += lds[w];
        lds[0] = r;
    }
    __syncthreads();
    float r = lds[0];
    __syncthreads();
    return r;
}

// ---------------- 1) normalize + hi/lo split, LDS-staged swizzled stores ----
// 256 blocks x 16 rows (was 128 x 32): at 128 blocks with 64 KB staging,
// half of the 256 CUs were provably idle. 16-row staging layout within a
// 32-row fragment block: per (step, k-half), the 16 rows' fragments are
// 128 contiguous elems at global offset (rb&1)*128 -> stores stay >=256 B
// coalesced segments.
__global__ void __launch_bounds__(256) norm_kernel(const float* __restrict__ zis,
                            const float* __restrict__ zjs,
                            ushort* __restrict__ zhi, ushort* __restrict__ zlo,
                            ushort* __restrict__ whi, ushort* __restrict__ wlo,
                            float* __restrict__ diag, float* __restrict__ acc) {
    __shared__ ushort st[4][4096];   // 32 KB staging (zhi,zlo,whi,wlo)
    int rb = blockIdx.x;             // 0..255, 16 rows each
    int wv = threadIdx.x >> 6, lane = threadIdx.x & 63;
    if (rb == 0) { acc[threadIdx.x] = 0.f; acc[threadIdx.x + 256] = 0.f; }
    for (int rr = 0; rr < 4; rr++) {
        int rloc = wv * 4 + rr;              // 0..15 within this block
        int r = rb * 16 + rloc;
        float4 zv = *(const float4*)&zis[r * DD + lane * 4];
        float4 wv4 = *(const float4*)&zjs[r * DD + lane * 4];
        float sz = zv.x * zv.x + zv.y * zv.y + zv.z * zv.z + zv.w * zv.w;
        float sw = wv4.x * wv4.x + wv4.y * wv4.y + wv4.z * wv4.z + wv4.w * wv4.w;
        float dt = zv.x * wv4.x + zv.y * wv4.y + zv.z * wv4.z + zv.w * wv4.w;
        for (int mask = 1; mask <= 32; mask <<= 1) {
            sz += __shfl_xor(sz, mask);
            sw += __shfl_xor(sw, mask);
            dt += __shfl_xor(dt, mask);
        }
        float iz = 1.0f / fmaxf(sqrtf(sz), 1e-12f);
        float iw = 1.0f / fmaxf(sqrtf(sw), 1e-12f);
        if (lane == 0) diag[r] = dt * iz * iw;
        float nz[4] = {zv.x * iz, zv.y * iz, zv.z * iz, zv.w * iz};
        float nw[4] = {wv4.x * iw, wv4.y * iw, wv4.z * iw, wv4.w * iw};
        for (int e = 0; e < 4; e++) {
            int k = lane * 4 + e;
            // 16-row local staging: step<<8 | khalf<<7 | rloc<<3 | pos
            int li = ((k >> 4) << 8) | (((((k >> 3) & 1) << 4) | rloc) << 3) | (k & 7);
            __hip_bfloat16 hz = __float2bfloat16(nz[e]);
            __hip_bfloat16 lz = __float2bfloat16(nz[e] - __bfloat162float(hz));
            __hip_bfloat16 hw = __float2bfloat16(nw[e]);
            __hip_bfloat16 lw = __float2bfloat16(nw[e] - __bfloat162float(hw));
            st[0][li] = *(ushort*)&hz;
            st[1][li] = *(ushort*)&lz;
            st[2][li] = *(ushort*)&hw;
            st[3][li] = *(ushort*)&lw;
        }
    }
    __syncthreads();
    // copy out: per array 512 uint4 (2 per thread).
    // local uint4 Lu: step=Lu>>5, khalf=(Lu>>4)&1, rloc=Lu&15
    // global uint4 Gu = (rb>>1)*1024 + step*64 + khalf*32 + (rb&1)*16 + rloc
    ushort* dsts[4] = {zhi, zlo, whi, wlo};
    int gbase = (rb >> 1) * 1024 + (rb & 1) * 16;
    for (int a = 0; a < 4; a++) {
        uint4* d = (uint4*)dsts[a];
        const uint4* s = (const uint4*)st[a];
        for (int it = 0; it < 2; it++) {
            int Lu = it * 256 + threadIdx.x;
            int Gu = gbase + (Lu >> 5) * 64 + ((Lu >> 4) & 1) * 32 + (Lu & 15);
            d[Gu] = s[Lu];
        }
    }
}

// ---------------- 2) fused tile: 128x64 block, 32x32x16 MFMA ---------------
// R3 structure (proven 270.2 us total): 6 MFMA/step main loop + LDS
// transpose row epilogue. Each wave dumps its 32x64 acc sub-tile into a
// stride-65 f32 buffer (bank=(row+col)%32: writes and row-reads both
// 2-way aliased = conflict-free per m136), then each lane owns one full
// row in-register. R4's (256,6)+tr16 squeeze regressed (VGPR cap 85 <
// ~88 live: MLP traded for TLP at a loss) -- reverted verbatim.
__global__ void __launch_bounds__(256, 4) fused_tile(const ushort* __restrict__ Ahi,
        const ushort* __restrict__ Alo, const ushort* __restrict__ Bhi,
        const ushort* __restrict__ Blo, const float* __restrict__ diag,
        const float* __restrict__ tausI, const float* __restrict__ tausT,
        const int* __restrict__ ids,
        float* __restrict__ pmR, float* __restrict__ pgR, float* __restrict__ pwR,
        float* __restrict__ pmC, float* __restrict__ pgC, float* __restrict__ pwC) {
    __shared__ float rDiag[128], rITau[128];
    __shared__ float cDiag[64], cITau[64];
    __shared__ float cmS[4][64], cgS[4][64], cwS[4][64];  // wave col partials
    __shared__ float tr[4][32 * 65];  // per-wave 32x64 transpose, stride 65

    int lane = threadIdx.x & 63;
    int wv = threadIdx.x >> 6;
    int bm = blockIdx.y * 128, bn = blockIdx.x * 64;
    int h = lane >> 5, cl = lane & 31;

    if (threadIdx.x < 128) {
        int r = bm + threadIdx.x;
        rDiag[threadIdx.x] = diag[r];
        rITau[threadIdx.x] = 1.0f / tausI[ids[r]];
    } else if (threadIdx.x < 192) {
        int c = bn + threadIdx.x - 128;
        cDiag[threadIdx.x - 128] = diag[c];
        cITau[threadIdx.x - 128] = 1.0f / tausT[ids[c]];
    }

    int aBase = (blockIdx.y * 4 + wv) * 8192;
    int b0 = (blockIdx.x * 2) * 8192;
    int b1 = b0 + 8192;
    int lofs = lane * 8;

    f32x16 acc[2] = {};   // sim: row(reg)=bm+wv*32+idx, col(lane)=bn+u*32+cl
#pragma unroll
    for (int s = 0; s < 16; s++) {
        int so = s * 512 + lofs;
        bf16x8 ah  = *(const bf16x8*)&Ahi[aBase + so];
        bf16x8 al  = *(const bf16x8*)&Alo[aBase + so];
        bf16x8 bh0 = *(const bf16x8*)&Bhi[b0 + so];
        bf16x8 bl0 = *(const bf16x8*)&Blo[b0 + so];
        bf16x8 bh1 = *(const bf16x8*)&Bhi[b1 + so];
        bf16x8 bl1 = *(const bf16x8*)&Blo[b1 + so];
        acc[0] = __builtin_amdgcn_mfma_f32_32x32x16_bf16(ah, bh0, acc[0], 0, 0, 0);
        acc[1] = __builtin_amdgcn_mfma_f32_32x32x16_bf16(ah, bh1, acc[1], 0, 0, 0);
        acc[0] = __builtin_amdgcn_mfma_f32_32x32x16_bf16(ah, bl0, acc[0], 0, 0, 0);
        acc[1] = __builtin_amdgcn_mfma_f32_32x32x16_bf16(ah, bl1, acc[1], 0, 0, 0);
        acc[0] = __builtin_amdgcn_mfma_f32_32x32x16_bf16(al, bh0, acc[0], 0, 0, 0);
        acc[1] = __builtin_amdgcn_mfma_f32_32x32x16_bf16(al, bh1, acc[1], 0, 0, 0);
    }

    // ---- col side (per wave: 64 cols x its 32 rows), in-register ----
    // C/D layout [m74/m101]: col=lane&31, row=(reg&3)+8*(reg>>2)+4*(lane>>5)
    __syncthreads();  // params visible
    float cd2[2], cit2[2], cbloc[2], cg[2] = {}, cw[2] = {};
#pragma unroll
    for (int u = 0; u < 2; u++) {
        int clc = u * 32 + cl;
        cd2[u] = cDiag[clc];
        cit2[u] = cITau[clc];
        float m = -INFINITY;
#pragma unroll
        for (int reg = 0; reg < 16; reg++) m = fmaxf(m, acc[u][reg]);
        m = fmaxf(m, __shfl_xor(m, 32));
        cbloc[u] = (m - cd2[u]) * cit2[u];
    }
#pragma unroll
    for (int u = 0; u < 2; u++) {
        int gc = bn + u * 32 + cl;
#pragma unroll
        for (int reg = 0; reg < 16; reg++) {
            int gr = bm + wv * 32 + (reg & 3) + 4 * h + 8 * (reg >> 2);
            float v = acc[u][reg];
            bool off = gr != gc;
            float dvT = v - cd2[u];
            float eT = off ? __expf(dvT * cit2[u] - cbloc[u]) : 0.f;
            cg[u] += eT;
            cw[u] += eT * dvT;
        }
    }
#pragma unroll
    for (int u = 0; u < 2; u++) {
        cg[u] += __shfl_xor(cg[u], 32);
        cw[u] += __shfl_xor(cw[u], 32);
        if (h == 0) {
            cmS[wv][u * 32 + cl] = cbloc[u];
            cgS[wv][u * 32 + cl] = cg[u];
            cwS[wv][u * 32 + cl] = cw[u];
        }
    }

    // ---- dump acc to per-wave LDS transpose buffer (stride 65) ----
#pragma unroll
    for (int u = 0; u < 2; u++)
#pragma unroll
        for (int reg = 0; reg < 16; reg++) {
            int r = (reg & 3) + 4 * h + 8 * (reg >> 2);
            tr[wv][r * 65 + u * 32 + cl] = acc[u][reg];
        }
    __syncthreads();  // cmS + tr visible

    // flash-combine 4 waves -> 1 col stripe per block (NSC=32)
    if (threadIdx.x < 64) {
        int c = threadIdx.x;
        float m = fmaxf(fmaxf(cmS[0][c], cmS[1][c]), fmaxf(cmS[2][c], cmS[3][c]));
        float g = 0.f, w = 0.f;
        for (int wq = 0; wq < 4; wq++) {
            float f = __expf(cmS[wq][c] - m);
            g += cgS[wq][c] * f;
            w += cwS[wq][c] * f;
        }
        size_t o = (size_t)blockIdx.y * BB + bn + c;
        pmC[o] = m;
        pgC[o] = g;
        pwC[o] = w;
    }

    // ---- row side from transpose: lane (cl,h) owns row cl, col half h ----
    {
        int r = cl;
        int grow = bm + wv * 32 + r;
        float rd = rDiag[wv * 32 + r];
        float rit = rITau[wv * 32 + r];
        float vv[32];
#pragma unroll
        for (int j = 0; j < 32; j++) vv[j] = tr[wv][r * 65 + h * 32 + j];
        float m = -INFINITY;
#pragma unroll
        for (int j = 0; j < 32; j++) m = fmaxf(m, vv[j]);
        m = fmaxf(m, __shfl_xor(m, 32));
        float bloc = (m - rd) * rit;
        float rg = 0.f, rw = 0.f;
#pragma unroll
        for (int j = 0; j < 32; j++) {
            int gc = bn + h * 32 + j;
            float dv = vv[j] - rd;
            float e = (grow != gc) ? __expf(dv * rit - bloc) : 0.f;
            rg += e;
            rw += e * dv;
        }
        rg += __shfl_xor(rg, 32);
        rw += __shfl_xor(rw, 32);
        if (h == 0) {
            size_t o = (size_t)blockIdx.x * BB + grow;
            pmR[o] = bloc;
            pgR[o] = rg;
            pwR[o] = rw;
        }
    }
}

// acc layout: [0]=lossI [1]=lossT [2..101]=gradI [102..201]=cntI
//             [202..301]=gradT [302..401]=cntT  [408]=completion counter(int)
// ---------------- 3) finalize: 256 blocks (2 sides x 128 chunks of 32 i) ---
// 256 threads = 32 i x 8 stripe-groups; online flash reduction per thread,
// LDS-combine across groups. 256 blocks = full CU coverage.
__global__ void __launch_bounds__(256) fin_kernel(
        const float* __restrict__ pmR, const float* __restrict__ pgR,
        const float* __restrict__ pwR, const float* __restrict__ pmC,
        const float* __restrict__ pgC, const float* __restrict__ pwC,
        const float* __restrict__ sI, const float* __restrict__ bI,
        const float* __restrict__ tausI, const int* __restrict__ gInfI,
        const float* __restrict__ pI,
        const float* __restrict__ sT, const float* __restrict__ bT,
        const float* __restrict__ tausT, const int* __restrict__ gInfT,
        const float* __restrict__ pT,
        const int* __restrict__ ids, float* __restrict__ acc,
        const float* __restrict__ zI, const float* __restrict__ zT,
        float* __restrict__ out) {
    __shared__ float lds[8];
    __shared__ float binF[GG], binC[GG];
    __shared__ float mS[8][32], gS[8][32], wS[8][32];
    __shared__ int lastFlag;
    if (threadIdx.x < GG) { binF[threadIdx.x] = 0.f; binC[threadIdx.x] = 0.f; }
    int side = blockIdx.x >> 7;
    int chunk = blockIdx.x & 127;
    int il = threadIdx.x & 31;
    int sg = threadIdx.x >> 5;
    int i = chunk * 32 + il;
    int ns = side ? NSC : NSR;
    const float* pm = side ? pmC : pmR;
    const float* pg = side ? pgC : pgR;
    const float* pw = side ? pwC : pwR;
    const float* sS = side ? sT : sI;
    const float* bS = side ? bT : bI;
    const float* taus = side ? tausT : tausI;
    const int* ginfo = side ? gInfT : gInfI;
    const float* pP = side ? pT : pI;

    // online flash over this group's stripes
    float m = -INFINITY, g = 0.f, w = 0.f;
    for (int s = sg; s < ns; s += 8) {
        float pms = pm[(size_t)s * BB + i];
        float pgs = pg[(size_t)s * BB + i];
        float pws = pw[(size_t)s * BB + i];
        float mn = fmaxf(m, pms);
        float fo = __expf(m - mn);
        float fs = __expf(pms - mn);
        g = g * fo + pgs * fs;
        w = w * fo + pws * fs;
        m = mn;
    }
    mS[sg][il] = m;
    gS[sg][il] = g;
    wS[sg][il] = w;
    __syncthreads();

    float loss = 0.f;
    if (sg == 0) {
        int id = ids[i];
        float oldb = bS[id];
        float mm = mS[0][il];
        for (int q = 1; q < 8; q++) mm = fmaxf(mm, mS[q][il]);
        float bfin = fmaxf(mm, oldb);
        float gg2 = 0.f, ww2 = 0.f;
        for (int q = 0; q < 8; q++) {
            float f = __expf(mS[q][il] - bfin);
            gg2 += gS[q][il] * f;
            ww2 += wS[q][il] * f;
        }
        float tau = taus[id];
        float snew = (1.f - GAMMA_C) * sS[id] * expf(oldb - bfin) + GAMMA_C * gg2;
        float sc = fmaxf(snew, EPS_C);
        int gid = ginfo[id];
        float gw = (float)GG * pP[gid];
        loss = gw * ww2 / sc;
        float F = tau * (logf(sc) + bfin + RHO_C);
        atomicAdd(&binF[gid], F);
        atomicAdd(&binC[gid], 1.0f);
    }
    float lsum = blockReduceSum(loss, lds);
    if (threadIdx.x == 0) atomicAdd(&acc[side], lsum);
    __syncthreads();
    if (threadIdx.x < GG) {
        atomicAdd(&acc[2 + side * 200 + threadIdx.x], binF[threadIdx.x]);
        atomicAdd(&acc[102 + side * 200 + threadIdx.x], binC[threadIdx.x]);
    }

    // ---- completion counter: last of 256 blocks runs the p-update phase ----
    __threadfence();
    if (threadIdx.x == 0) {
        int old = atomicAdd((int*)&acc[408], 1);
        lastFlag = (old == 255);
    }
    __syncthreads();
    if (!lastFlag) return;

    int gg = threadIdx.x;
    float npI = 0.f, npT = 0.f;
    if (gg < GG) {
        float cI = __hip_atomic_load(&acc[102 + gg], __ATOMIC_RELAXED, __HIP_MEMORY_SCOPE_AGENT);
        float fI = __hip_atomic_load(&acc[2 + gg], __ATOMIC_RELAXED, __HIP_MEMORY_SCOPE_AGENT);
        float gpI = fI / fmaxf(cI, 1.f);
        float zi = (1.f - GAMMA_C) * zI[gg] + GAMMA_C * gpI;
        float ghpI = -logf(pI[gg] + EPS_C) - 1.f;
        float ti = fminf(fmaxf(zi + ghpI, -5.f), 5.f);
        npI = pI[gg] * expf(0.02f * ti);

        float cT = __hip_atomic_load(&acc[302 + gg], __ATOMIC_RELAXED, __HIP_MEMORY_SCOPE_AGENT);
        float fT = __hip_atomic_load(&acc[202 + gg], __ATOMIC_RELAXED, __HIP_MEMORY_SCOPE_AGENT);
        float gpT = fT / fmaxf(cT, 1.f);
        float zt = (1.f - GAMMA_C) * zT[gg] + GAMMA_C * gpT;
        float ghpT = -logf(pT[gg] + EPS_C) - 1.f;
        float tt = fminf(fmaxf(zt + ghpT, -5.f), 5.f);
        npT = pT[gg] * expf(0.02f * tt);
    }
    float sumI = blockReduceSum(npI, lds);
    float sumT = blockReduceSum(npT, lds);
    if (gg < GG) {
        out[1 + gg] = npI / sumI;
        out[101 + gg] = npT / sumT;
    }
    if (gg == 0) {
        float lI = __hip_atomic_load(&acc[0], __ATOMIC_RELAXED, __HIP_MEMORY_SCOPE_AGENT);
        float lT = __hip_atomic_load(&acc[1], __ATOMIC_RELAXED, __HIP_MEMORY_SCOPE_AGENT);
        out[0] = ALPHA_C * (lI / (float)BB) + (1.f - ALPHA_C) * (lT / (float)BB);
    }
}

extern "C" void kernel_launch(void* const* d_in, const int* in_sizes, int n_in,
                              void* d_out, int out_size, void* d_ws, size_t ws_size,
                              hipStream_t stream) {
    const float* zis   = (const float*)d_in[0];
    const float* zjs   = (const float*)d_in[1];
    const float* s_I   = (const float*)d_in[2];
    const float* s_T   = (const float*)d_in[3];
    const float* b_I   = (const float*)d_in[4];
    const float* b_T   = (const float*)d_in[5];
    const float* z_I   = (const float*)d_in[6];
    const float* z_T   = (const float*)d_in[7];
    const float* p_I   = (const float*)d_in[8];
    const float* p_T   = (const float*)d_in[9];
    const float* tausI = (const float*)d_in[10];
    const float* tausT = (const float*)d_in[11];
    const int*   ids   = (const int*)d_in[12];
    const int*   gInfI = (const int*)d_in[13];
    const int*   gInfT = (const int*)d_in[14];
    float* out = (float*)d_out;

    char* ws = (char*)d_ws;
    ushort* zhi = (ushort*)ws;                         // BB*DD u16 each
    ushort* zlo = zhi + (size_t)BB * DD;
    ushort* whi = zlo + (size_t)BB * DD;
    ushort* wlo = whi + (size_t)BB * DD;
    float* acc  = (float*)(wlo + (size_t)BB * DD);     // 512
    float* diag = acc + 512;                           // BB
    float* pmR  = diag + BB;                           // NSR*BB each
    float* pgR  = pmR + (size_t)NSR * BB;
    float* pwR  = pgR + (size_t)NSR * BB;
    float* pmC  = pwR + (size_t)NSR * BB;              // NSC*BB each
    float* pgC  = pmC + (size_t)NSC * BB;
    float* pwC  = pgC + (size_t)NSC * BB;

    norm_kernel<<<256, 256, 0, stream>>>(zis, zjs, zhi, zlo, whi, wlo, diag, acc);
    fused_tile<<<dim3(64, 32), 256, 0, stream>>>(zhi, zlo, whi, wlo, diag,
            tausI, tausT, ids, pmR, pgR, pwR, pmC, pgC, pwC);
    fin_kernel<<<256, 256, 0, stream>>>(pmR, pgR, pwR, pmC, pgC, pwC,
            s_I, b_I, tausI, gInfI, p_I, s_T, b_T, tausT, gInfT, p_T, ids, acc,
            z_I, z_T, out);
}

// Round 6
// 271.773 us; speedup vs baseline: 1.0204x; 1.0037x over previous
//
#include <hip/hip_runtime.h>
#include <hip/hip_bf16.h>
#include <math.h>

#define BB 4096
#define DD 256
#define GG 100
#define GAMMA_C 0.8f
#define RHO_C 8.0f
#define ALPHA_C 0.5f
#define EPS_C 1e-14f
#define NSR 32    // row stripes (128-col tiles)
#define NSC 32    // col stripes (one per 128-row block; waves pre-combined)

typedef __bf16 bf16x8 __attribute__((ext_vector_type(8)));
typedef float f32x16 __attribute__((ext_vector_type(16)));

__device__ inline float blockReduceSum(float v, float* lds) {
    for (int o = 32; o > 0; o >>= 1) v += __shfl_down(v, o);
    int lane = threadIdx.x & 63, wid = threadIdx.x >> 6;
    if (lane == 0) lds[wid] = v;
    __syncthreads();
    if (threadIdx.x == 0) {
        float r = lds[0];
        int nw = blockDim.x >> 6;
        for (int w = 1; w < nw; w++) r += lds[w];
        lds[0] = r;
    }
    __syncthreads();
    float r = lds[0];
    __syncthreads();
    return r;
}

// ---------------- 1) normalize + hi/lo split, LDS-staged swizzled stores ----
// 256 blocks x 16 rows. 16-row staging layout within a 32-row fragment
// block: per (step, k-half) the 16 rows' fragments are 128 contiguous
// elems at global offset (rb&1)*128 -> stores stay >=256 B coalesced.
__global__ void __launch_bounds__(256) norm_kernel(const float* __restrict__ zis,
                            const float* __restrict__ zjs,
                            ushort* __restrict__ zhi, ushort* __restrict__ zlo,
                            ushort* __restrict__ whi, ushort* __restrict__ wlo,
                            float* __restrict__ diag, float* __restrict__ acc) {
    __shared__ ushort st[4][4096];   // 32 KB staging (zhi,zlo,whi,wlo)
    int rb = blockIdx.x;             // 0..255, 16 rows each
    int wv = threadIdx.x >> 6, lane = threadIdx.x & 63;
    if (rb == 0) { acc[threadIdx.x] = 0.f; acc[threadIdx.x + 256] = 0.f; }
    for (int rr = 0; rr < 4; rr++) {
        int rloc = wv * 4 + rr;              // 0..15 within this block
        int r = rb * 16 + rloc;
        float4 zv = *(const float4*)&zis[r * DD + lane * 4];
        float4 wv4 = *(const float4*)&zjs[r * DD + lane * 4];
        float sz = zv.x * zv.x + zv.y * zv.y + zv.z * zv.z + zv.w * zv.w;
        float sw = wv4.x * wv4.x + wv4.y * wv4.y + wv4.z * wv4.z + wv4.w * wv4.w;
        float dt = zv.x * wv4.x + zv.y * wv4.y + zv.z * wv4.z + zv.w * wv4.w;
        for (int mask = 1; mask <= 32; mask <<= 1) {
            sz += __shfl_xor(sz, mask);
            sw += __shfl_xor(sw, mask);
            dt += __shfl_xor(dt, mask);
        }
        float iz = 1.0f / fmaxf(sqrtf(sz), 1e-12f);
        float iw = 1.0f / fmaxf(sqrtf(sw), 1e-12f);
        if (lane == 0) diag[r] = dt * iz * iw;
        float nz[4] = {zv.x * iz, zv.y * iz, zv.z * iz, zv.w * iz};
        float nw[4] = {wv4.x * iw, wv4.y * iw, wv4.z * iw, wv4.w * iw};
        for (int e = 0; e < 4; e++) {
            int k = lane * 4 + e;
            // 16-row local staging: step<<8 | khalf<<7 | rloc<<3 | pos
            int li = ((k >> 4) << 8) | (((((k >> 3) & 1) << 4) | rloc) << 3) | (k & 7);
            __hip_bfloat16 hz = __float2bfloat16(nz[e]);
            __hip_bfloat16 lz = __float2bfloat16(nz[e] - __bfloat162float(hz));
            __hip_bfloat16 hw = __float2bfloat16(nw[e]);
            __hip_bfloat16 lw = __float2bfloat16(nw[e] - __bfloat162float(hw));
            st[0][li] = *(ushort*)&hz;
            st[1][li] = *(ushort*)&lz;
            st[2][li] = *(ushort*)&hw;
            st[3][li] = *(ushort*)&lw;
        }
    }
    __syncthreads();
    // copy out: per array 512 uint4 (2 per thread).
    // local uint4 Lu: step=Lu>>5, khalf=(Lu>>4)&1, rloc=Lu&15
    // global uint4 Gu = (rb>>1)*1024 + step*64 + khalf*32 + (rb&1)*16 + rloc
    ushort* dsts[4] = {zhi, zlo, whi, wlo};
    int gbase = (rb >> 1) * 1024 + (rb & 1) * 16;
    for (int a = 0; a < 4; a++) {
        uint4* d = (uint4*)dsts[a];
        const uint4* s = (const uint4*)st[a];
        for (int it = 0; it < 2; it++) {
            int Lu = it * 256 + threadIdx.x;
            int Gu = gbase + (Lu >> 5) * 64 + ((Lu >> 4) & 1) * 32 + (Lu & 15);
            d[Gu] = s[Lu];
        }
    }
}

// ---------------- 2) fused tile: 128x128 block, 32x32x16 MFMA --------------
// Tile-up from 128x64: 12 MFMA : 10 loads per step (was 6:6) -> higher
// arithmetic intensity per L2 round-trip, 1024 blocks = exactly one
// dispatch round at 4 blocks/CU. Row-side epilogue reuses the proven
// 32x65 tr buffer in TWO sequential col-half rounds with in-register
// flash merge (wave-internal DS ordering, no extra barriers; all tr
// accesses 2-way bank-aliased = free per m136).
__global__ void __launch_bounds__(256, 4) fused_tile(const ushort* __restrict__ Ahi,
        const ushort* __restrict__ Alo, const ushort* __restrict__ Bhi,
        const ushort* __restrict__ Blo, const float* __restrict__ diag,
        const float* __restrict__ tausI, const float* __restrict__ tausT,
        const int* __restrict__ ids,
        float* __restrict__ pmR, float* __restrict__ pgR, float* __restrict__ pwR,
        float* __restrict__ pmC, float* __restrict__ pgC, float* __restrict__ pwC) {
    __shared__ float rDiag[128], rITau[128];
    __shared__ float cDiag[128], cITau[128];
    __shared__ float cmS[4][128], cgS[4][128], cwS[4][128];  // wave col partials
    __shared__ float tr[4][32 * 65];  // per-wave 32x64 transpose, stride 65

    int lane = threadIdx.x & 63;
    int wv = threadIdx.x >> 6;
    int bm = blockIdx.y * 128, bn = blockIdx.x * 128;
    int h = lane >> 5, cl = lane & 31;

    if (threadIdx.x < 128) {
        int r = bm + threadIdx.x;
        rDiag[threadIdx.x] = diag[r];
        rITau[threadIdx.x] = 1.0f / tausI[ids[r]];
    } else {
        int c = bn + threadIdx.x - 128;
        cDiag[threadIdx.x - 128] = diag[c];
        cITau[threadIdx.x - 128] = 1.0f / tausT[ids[c]];
    }

    int aBase = (blockIdx.y * 4 + wv) * 8192;
    int bB0 = (blockIdx.x * 4) * 8192;
    int lofs = lane * 8;

    f32x16 acc[4] = {};   // sim: row(reg)=bm+wv*32+idx, col(lane)=bn+u*32+cl
#pragma unroll
    for (int s = 0; s < 16; s++) {
        int so = s * 512 + lofs;
        bf16x8 ah = *(const bf16x8*)&Ahi[aBase + so];
        bf16x8 al = *(const bf16x8*)&Alo[aBase + so];
        bf16x8 bh[4], bl[4];
#pragma unroll
        for (int j = 0; j < 4; j++) {
            bh[j] = *(const bf16x8*)&Bhi[bB0 + j * 8192 + so];
            bl[j] = *(const bf16x8*)&Blo[bB0 + j * 8192 + so];
        }
        // j-major order: 4 independent accumulator chains per pass
#pragma unroll
        for (int j = 0; j < 4; j++)
            acc[j] = __builtin_amdgcn_mfma_f32_32x32x16_bf16(ah, bh[j], acc[j], 0, 0, 0);
#pragma unroll
        for (int j = 0; j < 4; j++)
            acc[j] = __builtin_amdgcn_mfma_f32_32x32x16_bf16(ah, bl[j], acc[j], 0, 0, 0);
#pragma unroll
        for (int j = 0; j < 4; j++)
            acc[j] = __builtin_amdgcn_mfma_f32_32x32x16_bf16(al, bh[j], acc[j], 0, 0, 0);
    }

    // ---- col side (per wave: 128 cols x its 32 rows), in-register ----
    // C/D layout [m74/m101]: col=lane&31, row=(reg&3)+8*(reg>>2)+4*(lane>>5)
    __syncthreads();  // params visible
#pragma unroll
    for (int u = 0; u < 4; u++) {
        int clc = u * 32 + cl;
        float cd = cDiag[clc];
        float cit = cITau[clc];
        float m = -INFINITY;
#pragma unroll
        for (int reg = 0; reg < 16; reg++) m = fmaxf(m, acc[u][reg]);
        m = fmaxf(m, __shfl_xor(m, 32));
        float cb = (m - cd) * cit;
        float cg = 0.f, cw = 0.f;
        int gc = bn + clc;
#pragma unroll
        for (int reg = 0; reg < 16; reg++) {
            int gr = bm + wv * 32 + (reg & 3) + 4 * h + 8 * (reg >> 2);
            float v = acc[u][reg];
            bool off = gr != gc;
            float dvT = v - cd;
            float eT = off ? __expf(dvT * cit - cb) : 0.f;
            cg += eT;
            cw += eT * dvT;
        }
        cg += __shfl_xor(cg, 32);
        cw += __shfl_xor(cw, 32);
        if (h == 0) {
            cmS[wv][clc] = cb;
            cgS[wv][clc] = cg;
            cwS[wv][clc] = cw;
        }
    }
    __syncthreads();  // cmS visible

    // flash-combine 4 waves -> 1 col stripe per block (NSC=32)
    if (threadIdx.x < 128) {
        int c = threadIdx.x;
        float m = fmaxf(fmaxf(cmS[0][c], cmS[1][c]), fmaxf(cmS[2][c], cmS[3][c]));
        float g = 0.f, w = 0.f;
        for (int wq = 0; wq < 4; wq++) {
            float f = __expf(cmS[wq][c] - m);
            g += cgS[wq][c] * f;
            w += cwS[wq][c] * f;
        }
        size_t o = (size_t)blockIdx.y * BB + bn + c;
        pmC[o] = m;
        pgC[o] = g;
        pwC[o] = w;
    }

    // ---- row side: 2 col-half rounds through per-wave tr (no barriers:
    //      each wave only touches tr[wv]; in-order per-wave DS + lgkmcnt) --
    {
        int grow = bm + wv * 32 + cl;
        float rd = rDiag[wv * 32 + cl];
        float rit = rITau[wv * 32 + cl];
        float rm = -INFINITY, rg = 0.f, rw = 0.f;
#pragma unroll
        for (int ch = 0; ch < 2; ch++) {
            // dump acc[2ch], acc[2ch+1] (cols ch*64 .. ch*64+63)
#pragma unroll
            for (int uu = 0; uu < 2; uu++)
#pragma unroll
                for (int reg = 0; reg < 16; reg++) {
                    int r = (reg & 3) + 4 * h + 8 * (reg >> 2);
                    tr[wv][r * 65 + uu * 32 + cl] = acc[ch * 2 + uu][reg];
                }
            // lane (cl,h) reads row cl, cols h*32..h*32+31 of this half
            float vv[32];
#pragma unroll
            for (int j = 0; j < 32; j++) vv[j] = tr[wv][cl * 65 + h * 32 + j];
            float m0 = -INFINITY;
#pragma unroll
            for (int j = 0; j < 32; j++) m0 = fmaxf(m0, vv[j]);
            float g0 = 0.f, w0 = 0.f;
#pragma unroll
            for (int j = 0; j < 32; j++) {
                int gc = bn + ch * 64 + h * 32 + j;
                float dv = vv[j] - rd;
                float e = (grow != gc) ? __expf((vv[j] - m0) * rit) : 0.f;
                g0 += e;
                w0 += e * dv;
            }
            // flash-merge round into (rm, rg, rw)
            float mn = fmaxf(rm, m0);
            float fo = __expf((rm - mn) * rit);   // exp(-inf)=0 on first round
            float fs = __expf((m0 - mn) * rit);
            rg = rg * fo + g0 * fs;
            rw = rw * fo + w0 * fs;
            rm = mn;
        }
        // combine h halves
        float mo = __shfl_xor(rm, 32);
        float go = __shfl_xor(rg, 32);
        float wo = __shfl_xor(rw, 32);
        float mn = fmaxf(rm, mo);
        rg = rg * __expf((rm - mn) * rit) + go * __expf((mo - mn) * rit);
        rw = rw * __expf((rm - mn) * rit) + wo * __expf((mo - mn) * rit);
        rm = mn;
        float bloc = (rm - rd) * rit;
        if (h == 0) {
            size_t o = (size_t)blockIdx.x * BB + grow;
            pmR[o] = bloc;
            pgR[o] = rg;
            pwR[o] = rw;
        }
    }
}

// acc layout: [0]=lossI [1]=lossT [2..101]=gradI [102..201]=cntI
//             [202..301]=gradT [302..401]=cntT  [408]=completion counter(int)
// ---------------- 3) finalize: 256 blocks (2 sides x 128 chunks of 32 i) ---
// 256 threads = 32 i x 8 stripe-groups; online flash reduction per thread,
// LDS-combine across groups. 256 blocks = full CU coverage.
__global__ void __launch_bounds__(256) fin_kernel(
        const float* __restrict__ pmR, const float* __restrict__ pgR,
        const float* __restrict__ pwR, const float* __restrict__ pmC,
        const float* __restrict__ pgC, const float* __restrict__ pwC,
        const float* __restrict__ sI, const float* __restrict__ bI,
        const float* __restrict__ tausI, const int* __restrict__ gInfI,
        const float* __restrict__ pI,
        const float* __restrict__ sT, const float* __restrict__ bT,
        const float* __restrict__ tausT, const int* __restrict__ gInfT,
        const float* __restrict__ pT,
        const int* __restrict__ ids, float* __restrict__ acc,
        const float* __restrict__ zI, const float* __restrict__ zT,
        float* __restrict__ out) {
    __shared__ float lds[8];
    __shared__ float binF[GG], binC[GG];
    __shared__ float mS[8][32], gS[8][32], wS[8][32];
    __shared__ int lastFlag;
    if (threadIdx.x < GG) { binF[threadIdx.x] = 0.f; binC[threadIdx.x] = 0.f; }
    int side = blockIdx.x >> 7;
    int chunk = blockIdx.x & 127;
    int il = threadIdx.x & 31;
    int sg = threadIdx.x >> 5;
    int i = chunk * 32 + il;
    int ns = side ? NSC : NSR;
    const float* pm = side ? pmC : pmR;
    const float* pg = side ? pgC : pgR;
    const float* pw = side ? pwC : pwR;
    const float* sS = side ? sT : sI;
    const float* bS = side ? bT : bI;
    const float* taus = side ? tausT : tausI;
    const int* ginfo = side ? gInfT : gInfI;
    const float* pP = side ? pT : pI;

    // online flash over this group's stripes
    float m = -INFINITY, g = 0.f, w = 0.f;
    for (int s = sg; s < ns; s += 8) {
        float pms = pm[(size_t)s * BB + i];
        float pgs = pg[(size_t)s * BB + i];
        float pws = pw[(size_t)s * BB + i];
        float mn = fmaxf(m, pms);
        float fo = __expf(m - mn);
        float fs = __expf(pms - mn);
        g = g * fo + pgs * fs;
        w = w * fo + pws * fs;
        m = mn;
    }
    mS[sg][il] = m;
    gS[sg][il] = g;
    wS[sg][il] = w;
    __syncthreads();

    float loss = 0.f;
    if (sg == 0) {
        int id = ids[i];
        float oldb = bS[id];
        float mm = mS[0][il];
        for (int q = 1; q < 8; q++) mm = fmaxf(mm, mS[q][il]);
        float bfin = fmaxf(mm, oldb);
        float gg2 = 0.f, ww2 = 0.f;
        for (int q = 0; q < 8; q++) {
            float f = __expf(mS[q][il] - bfin);
            gg2 += gS[q][il] * f;
            ww2 += wS[q][il] * f;
        }
        float tau = taus[id];
        float snew = (1.f - GAMMA_C) * sS[id] * expf(oldb - bfin) + GAMMA_C * gg2;
        float sc = fmaxf(snew, EPS_C);
        int gid = ginfo[id];
        float gw = (float)GG * pP[gid];
        loss = gw * ww2 / sc;
        float F = tau * (logf(sc) + bfin + RHO_C);
        atomicAdd(&binF[gid], F);
        atomicAdd(&binC[gid], 1.0f);
    }
    float lsum = blockReduceSum(loss, lds);
    if (threadIdx.x == 0) atomicAdd(&acc[side], lsum);
    __syncthreads();
    if (threadIdx.x < GG) {
        atomicAdd(&acc[2 + side * 200 + threadIdx.x], binF[threadIdx.x]);
        atomicAdd(&acc[102 + side * 200 + threadIdx.x], binC[threadIdx.x]);
    }

    // ---- completion counter: last of 256 blocks runs the p-update phase ----
    __threadfence();
    if (threadIdx.x == 0) {
        int old = atomicAdd((int*)&acc[408], 1);
        lastFlag = (old == 255);
    }
    __syncthreads();
    if (!lastFlag) return;

    int gg = threadIdx.x;
    float npI = 0.f, npT = 0.f;
    if (gg < GG) {
        float cI = __hip_atomic_load(&acc[102 + gg], __ATOMIC_RELAXED, __HIP_MEMORY_SCOPE_AGENT);
        float fI = __hip_atomic_load(&acc[2 + gg], __ATOMIC_RELAXED, __HIP_MEMORY_SCOPE_AGENT);
        float gpI = fI / fmaxf(cI, 1.f);
        float zi = (1.f - GAMMA_C) * zI[gg] + GAMMA_C * gpI;
        float ghpI = -logf(pI[gg] + EPS_C) - 1.f;
        float ti = fminf(fmaxf(zi + ghpI, -5.f), 5.f);
        npI = pI[gg] * expf(0.02f * ti);

        float cT = __hip_atomic_load(&acc[302 + gg], __ATOMIC_RELAXED, __HIP_MEMORY_SCOPE_AGENT);
        float fT = __hip_atomic_load(&acc[202 + gg], __ATOMIC_RELAXED, __HIP_MEMORY_SCOPE_AGENT);
        float gpT = fT / fmaxf(cT, 1.f);
        float zt = (1.f - GAMMA_C) * zT[gg] + GAMMA_C * gpT;
        float ghpT = -logf(pT[gg] + EPS_C) - 1.f;
        float tt = fminf(fmaxf(zt + ghpT, -5.f), 5.f);
        npT = pT[gg] * expf(0.02f * tt);
    }
    float sumI = blockReduceSum(npI, lds);
    float sumT = blockReduceSum(npT, lds);
    if (gg < GG) {
        out[1 + gg] = npI / sumI;
        out[101 + gg] = npT / sumT;
    }
    if (gg == 0) {
        float lI = __hip_atomic_load(&acc[0], __ATOMIC_RELAXED, __HIP_MEMORY_SCOPE_AGENT);
        float lT = __hip_atomic_load(&acc[1], __ATOMIC_RELAXED, __HIP_MEMORY_SCOPE_AGENT);
        out[0] = ALPHA_C * (lI / (float)BB) + (1.f - ALPHA_C) * (lT / (float)BB);
    }
}

extern "C" void kernel_launch(void* const* d_in, const int* in_sizes, int n_in,
                              void* d_out, int out_size, void* d_ws, size_t ws_size,
                              hipStream_t stream) {
    const float* zis   = (const float*)d_in[0];
    const float* zjs   = (const float*)d_in[1];
    const float* s_I   = (const float*)d_in[2];
    const float* s_T   = (const float*)d_in[3];
    const float* b_I   = (const float*)d_in[4];
    const float* b_T   = (const float*)d_in[5];
    const float* z_I   = (const float*)d_in[6];
    const float* z_T   = (const float*)d_in[7];
    const float* p_I   = (const float*)d_in[8];
    const float* p_T   = (const float*)d_in[9];
    const float* tausI = (const float*)d_in[10];
    const float* tausT = (const float*)d_in[11];
    const int*   ids   = (const int*)d_in[12];
    const int*   gInfI = (const int*)d_in[13];
    const int*   gInfT = (const int*)d_in[14];
    float* out = (float*)d_out;

    char* ws = (char*)d_ws;
    ushort* zhi = (ushort*)ws;                         // BB*DD u16 each
    ushort* zlo = zhi + (size_t)BB * DD;
    ushort* whi = zlo + (size_t)BB * DD;
    ushort* wlo = whi + (size_t)BB * DD;
    float* acc  = (float*)(wlo + (size_t)BB * DD);     // 512
    float* diag = acc + 512;                           // BB
    float* pmR  = diag + BB;                           // NSR*BB each
    float* pgR  = pmR + (size_t)NSR * BB;
    float* pwR  = pgR + (size_t)NSR * BB;
    float* pmC  = pwR + (size_t)NSR * BB;              // NSC*BB each
    float* pgC  = pmC + (size_t)NSC * BB;
    float* pwC  = pgC + (size_t)NSC * BB;

    norm_kernel<<<256, 256, 0, stream>>>(zis, zjs, zhi, zlo, whi, wlo, diag, acc);
    fused_tile<<<dim3(32, 32), 256, 0, stream>>>(zhi, zlo, whi, wlo, diag,
            tausI, tausT, ids, pmR, pgR, pwR, pmC, pgC, pwC);
    fin_kernel<<<256, 256, 0, stream>>>(pmR, pgR, pwR, pmC, pgC, pwC,
            s_I, b_I, tausI, gInfI, p_I, s_T, b_T, tausT, gInfT, p_T, ids, acc,
            z_I, z_T, out);
}

// Round 7
// 269.262 us; speedup vs baseline: 1.0300x; 1.0093x over previous
//
#include <hip/hip_runtime.h>
#include <hip/hip_bf16.h>
#include <math.h>

#define BB 4096
#define DD 256
#define GG 100
#define GAMMA_C 0.8f
#define RHO_C 8.0f
#define ALPHA_C 0.5f
#define EPS_C 1e-14f
#define NSR 32    // row stripes (128-col tiles)
#define NSC 32    // col stripes (one per 128-row block; waves pre-combined)

typedef __bf16 bf16x8 __attribute__((ext_vector_type(8)));
typedef float f32x16 __attribute__((ext_vector_type(16)));

__device__ inline float blockReduceSum(float v, float* lds) {
    for (int o = 32; o > 0; o >>= 1) v += __shfl_down(v, o);
    int lane = threadIdx.x & 63, wid = threadIdx.x >> 6;
    if (lane == 0) lds[wid] = v;
    __syncthreads();
    if (threadIdx.x == 0) {
        float r = lds[0];
        int nw = blockDim.x >> 6;
        for (int w = 1; w < nw; w++) r += lds[w];
        lds[0] = r;
    }
    __syncthreads();
    float r = lds[0];
    __syncthreads();
    return r;
}

// ---------------- 1) normalize + hi/lo split, LDS-staged swizzled stores ----
// 256 blocks x 16 rows. 16-row staging layout within a 32-row fragment
// block: per (step, k-half) the 16 rows' fragments are 128 contiguous
// elems at global offset (rb&1)*128 -> stores stay >=256 B coalesced.
__global__ void __launch_bounds__(256) norm_kernel(const float* __restrict__ zis,
                            const float* __restrict__ zjs,
                            ushort* __restrict__ zhi, ushort* __restrict__ zlo,
                            ushort* __restrict__ whi, ushort* __restrict__ wlo,
                            float* __restrict__ diag, float* __restrict__ acc) {
    __shared__ ushort st[4][4096];   // 32 KB staging (zhi,zlo,whi,wlo)
    int rb = blockIdx.x;             // 0..255, 16 rows each
    int wv = threadIdx.x >> 6, lane = threadIdx.x & 63;
    if (rb == 0) { acc[threadIdx.x] = 0.f; acc[threadIdx.x + 256] = 0.f; }
    for (int rr = 0; rr < 4; rr++) {
        int rloc = wv * 4 + rr;              // 0..15 within this block
        int r = rb * 16 + rloc;
        float4 zv = *(const float4*)&zis[r * DD + lane * 4];
        float4 wv4 = *(const float4*)&zjs[r * DD + lane * 4];
        float sz = zv.x * zv.x + zv.y * zv.y + zv.z * zv.z + zv.w * zv.w;
        float sw = wv4.x * wv4.x + wv4.y * wv4.y + wv4.z * wv4.z + wv4.w * wv4.w;
        float dt = zv.x * wv4.x + zv.y * wv4.y + zv.z * wv4.z + zv.w * wv4.w;
        for (int mask = 1; mask <= 32; mask <<= 1) {
            sz += __shfl_xor(sz, mask);
            sw += __shfl_xor(sw, mask);
            dt += __shfl_xor(dt, mask);
        }
        float iz = 1.0f / fmaxf(sqrtf(sz), 1e-12f);
        float iw = 1.0f / fmaxf(sqrtf(sw), 1e-12f);
        if (lane == 0) diag[r] = dt * iz * iw;
        float nz[4] = {zv.x * iz, zv.y * iz, zv.z * iz, zv.w * iz};
        float nw[4] = {wv4.x * iw, wv4.y * iw, wv4.z * iw, wv4.w * iw};
        for (int e = 0; e < 4; e++) {
            int k = lane * 4 + e;
            // 16-row local staging: step<<8 | khalf<<7 | rloc<<3 | pos
            int li = ((k >> 4) << 8) | (((((k >> 3) & 1) << 4) | rloc) << 3) | (k & 7);
            __hip_bfloat16 hz = __float2bfloat16(nz[e]);
            __hip_bfloat16 lz = __float2bfloat16(nz[e] - __bfloat162float(hz));
            __hip_bfloat16 hw = __float2bfloat16(nw[e]);
            __hip_bfloat16 lw = __float2bfloat16(nw[e] - __bfloat162float(hw));
            st[0][li] = *(ushort*)&hz;
            st[1][li] = *(ushort*)&lz;
            st[2][li] = *(ushort*)&hw;
            st[3][li] = *(ushort*)&lw;
        }
    }
    __syncthreads();
    // copy out: per array 512 uint4 (2 per thread).
    // local uint4 Lu: step=Lu>>5, khalf=(Lu>>4)&1, rloc=Lu&15
    // global uint4 Gu = (rb>>1)*1024 + step*64 + khalf*32 + (rb&1)*16 + rloc
    ushort* dsts[4] = {zhi, zlo, whi, wlo};
    int gbase = (rb >> 1) * 1024 + (rb & 1) * 16;
    for (int a = 0; a < 4; a++) {
        uint4* d = (uint4*)dsts[a];
        const uint4* s = (const uint4*)st[a];
        for (int it = 0; it < 2; it++) {
            int Lu = it * 256 + threadIdx.x;
            int Gu = gbase + (Lu >> 5) * 64 + ((Lu >> 4) & 1) * 32 + (Lu & 15);
            d[Gu] = s[Lu];
        }
    }
}

// ---------------- 2) fused tile: 128x128 block, LDS-staged B ---------------
// R6 was L2-BW-bound: 4 waves redundantly loaded the same 32 KB of B per
// step (655 MB of L2 traffic/dispatch ~ 19 us floor). Now B is staged in a
// double-buffered LDS tile ONCE per block (reg-staged, T14 split: global
// loads issued at step top, ds_writes after the MFMAs so L2 latency hides
// under compute; __syncthreads' vmcnt+lgkm drain publishes the buffer).
// L2 traffic 655 -> 262 MB. LDS pool (33.3 KB) aliases {B-dbuf 16 KB |
// col partials 6 KB | tr epilogue 33.3 KB} which are temporally disjoint;
// +2 KB params = 35.3 KB -> 4 blocks/CU. MFMA order per accumulator is
// identical to R6 (bit-exact epilogue preserved).
#define BSTG(p, st2, e) (((ushort*)pool)[((p) * 8 + (st2)) * 512 + (e)])
__global__ void __launch_bounds__(256, 4) fused_tile(const ushort* __restrict__ Ahi,
        const ushort* __restrict__ Alo, const ushort* __restrict__ Bhi,
        const ushort* __restrict__ Blo, const float* __restrict__ diag,
        const float* __restrict__ tausI, const float* __restrict__ tausT,
        const int* __restrict__ ids,
        float* __restrict__ pmR, float* __restrict__ pgR, float* __restrict__ pwR,
        float* __restrict__ pmC, float* __restrict__ pgC, float* __restrict__ pwC) {
    __shared__ float rDiag[128], rITau[128];
    __shared__ float cDiag[128], cITau[128];
    __shared__ alignas(16) char pool[33280];  // max(bstg 16K, colP 6K, tr 33.3K)

    int lane = threadIdx.x & 63;
    int wv = threadIdx.x >> 6;
    int bm = blockIdx.y * 128, bn = blockIdx.x * 128;
    int h = lane >> 5, cl = lane & 31;

    if (threadIdx.x < 128) {
        int r = bm + threadIdx.x;
        rDiag[threadIdx.x] = diag[r];
        rITau[threadIdx.x] = 1.0f / tausI[ids[r]];
    } else {
        int c = bn + threadIdx.x - 128;
        cDiag[threadIdx.x - 128] = diag[c];
        cITau[threadIdx.x - 128] = 1.0f / tausT[ids[c]];
    }

    int aBase = (blockIdx.y * 4 + wv) * 8192;
    int bB0 = (blockIdx.x * 4) * 8192;
    int lofs = lane * 8;

    // this wave stages streams {st0, st0+1}: wv0->Bhi0,1  wv1->Bhi2,3
    //                                        wv2->Blo0,1  wv3->Blo2,3
    int st0 = wv * 2;
    const ushort* sgA = ((wv & 2) ? Blo : Bhi) + bB0 + (st0 & 3) * 8192;
    const ushort* sgB = sgA + 8192;

    // prologue: stage step 0 into buffer 0
    {
        uint4 p0 = *(const uint4*)(sgA + lofs);
        uint4 p1 = *(const uint4*)(sgB + lofs);
        *(uint4*)&BSTG(0, st0, lofs) = p0;
        *(uint4*)&BSTG(0, st0 + 1, lofs) = p1;
    }
    __syncthreads();

    f32x16 acc[4] = {};   // sim: row(reg)=bm+wv*32+idx, col(lane)=bn+u*32+cl
#pragma unroll
    for (int s = 0; s < 16; s++) {
        const int cur = s & 1;
        uint4 sr0, sr1;
        if (s < 15) {   // issue next-step B loads early (latency under MFMAs)
            sr0 = *(const uint4*)(sgA + (s + 1) * 512 + lofs);
            sr1 = *(const uint4*)(sgB + (s + 1) * 512 + lofs);
        }
        int so = s * 512 + lofs;
        bf16x8 ah = *(const bf16x8*)&Ahi[aBase + so];
        bf16x8 al = *(const bf16x8*)&Alo[aBase + so];
        bf16x8 bh[4], bl[4];
#pragma unroll
        for (int j = 0; j < 4; j++) {
            bh[j] = *(const bf16x8*)&BSTG(cur, j, lofs);
            bl[j] = *(const bf16x8*)&BSTG(cur, 4 + j, lofs);
        }
        // j-major order (identical per-acc sequence to R6: hb, lb... hi*lo)
#pragma unroll
        for (int j = 0; j < 4; j++)
            acc[j] = __builtin_amdgcn_mfma_f32_32x32x16_bf16(ah, bh[j], acc[j], 0, 0, 0);
#pragma unroll
        for (int j = 0; j < 4; j++)
            acc[j] = __builtin_amdgcn_mfma_f32_32x32x16_bf16(ah, bl[j], acc[j], 0, 0, 0);
#pragma unroll
        for (int j = 0; j < 4; j++)
            acc[j] = __builtin_amdgcn_mfma_f32_32x32x16_bf16(al, bh[j], acc[j], 0, 0, 0);
        if (s < 15) {   // late write: vmcnt wait lands after the MFMA cluster
            *(uint4*)&BSTG(cur ^ 1, st0, lofs) = sr0;
            *(uint4*)&BSTG(cur ^ 1, st0 + 1, lofs) = sr1;
        }
        __syncthreads();   // publish staged buffer; ds_reads of cur drained
    }

    // ---- col side (per wave: 128 cols x its 32 rows), in-register ----
    // C/D layout [m74/m101]: col=lane&31, row=(reg&3)+8*(reg>>2)+4*(lane>>5)
    // partials go into pool (bstg is dead after the final step barrier)
    float* CM = (float*)pool;          // [4][128]
    float* CGp = CM + 512;
    float* CWp = CM + 1024;
#pragma unroll
    for (int u = 0; u < 4; u++) {
        int clc = u * 32 + cl;
        float cd = cDiag[clc];
        float cit = cITau[clc];
        float m = -INFINITY;
#pragma unroll
        for (int reg = 0; reg < 16; reg++) m = fmaxf(m, acc[u][reg]);
        m = fmaxf(m, __shfl_xor(m, 32));
        float cb = (m - cd) * cit;
        float cg = 0.f, cw = 0.f;
        int gc = bn + clc;
#pragma unroll
        for (int reg = 0; reg < 16; reg++) {
            int gr = bm + wv * 32 + (reg & 3) + 4 * h + 8 * (reg >> 2);
            float v = acc[u][reg];
            bool off = gr != gc;
            float dvT = v - cd;
            float eT = off ? __expf(dvT * cit - cb) : 0.f;
            cg += eT;
            cw += eT * dvT;
        }
        cg += __shfl_xor(cg, 32);
        cw += __shfl_xor(cw, 32);
        if (h == 0) {
            CM[wv * 128 + clc] = cb;
            CGp[wv * 128 + clc] = cg;
            CWp[wv * 128 + clc] = cw;
        }
    }
    __syncthreads();  // partials visible

    // flash-combine 4 waves -> 1 col stripe per block (NSC=32)
    if (threadIdx.x < 128) {
        int c = threadIdx.x;
        float m = fmaxf(fmaxf(CM[c], CM[128 + c]), fmaxf(CM[256 + c], CM[384 + c]));
        float g = 0.f, w = 0.f;
        for (int wq = 0; wq < 4; wq++) {
            float f = __expf(CM[wq * 128 + c] - m);
            g += CGp[wq * 128 + c] * f;
            w += CWp[wq * 128 + c] * f;
        }
        size_t o = (size_t)blockIdx.y * BB + bn + c;
        pmC[o] = m;
        pgC[o] = g;
        pwC[o] = w;
    }
    __syncthreads();  // col-combine done reading pool -> tr may overwrite

    // ---- row side: 2 col-half rounds through per-wave tr (stride 65,
    //      2-way bank-aliased = free; wave-private, lgkmcnt-ordered) ----
    {
        float* trF = (float*)pool + wv * 2080;   // 32*65 per wave
        int grow = bm + wv * 32 + cl;
        float rd = rDiag[wv * 32 + cl];
        float rit = rITau[wv * 32 + cl];
        float rm = -INFINITY, rg = 0.f, rw = 0.f;
#pragma unroll
        for (int ch = 0; ch < 2; ch++) {
            // dump acc[2ch], acc[2ch+1] (cols ch*64 .. ch*64+63)
#pragma unroll
            for (int uu = 0; uu < 2; uu++)
#pragma unroll
                for (int reg = 0; reg < 16; reg++) {
                    int r = (reg & 3) + 4 * h + 8 * (reg >> 2);
                    trF[r * 65 + uu * 32 + cl] = acc[ch * 2 + uu][reg];
                }
            // lane (cl,h) reads row cl, cols h*32..h*32+31 of this half
            float vv[32];
#pragma unroll
            for (int j = 0; j < 32; j++) vv[j] = trF[cl * 65 + h * 32 + j];
            float m0 = -INFINITY;
#pragma unroll
            for (int j = 0; j < 32; j++) m0 = fmaxf(m0, vv[j]);
            float g0 = 0.f, w0 = 0.f;
#pragma unroll
            for (int j = 0; j < 32; j++) {
                int gc = bn + ch * 64 + h * 32 + j;
                float dv = vv[j] - rd;
                float e = (grow != gc) ? __expf((vv[j] - m0) * rit) : 0.f;
                g0 += e;
                w0 += e * dv;
            }
            // flash-merge round into (rm, rg, rw)
            float mn = fmaxf(rm, m0);
            float fo = __expf((rm - mn) * rit);   // exp(-inf)=0 on first round
            float fs = __expf((m0 - mn) * rit);
            rg = rg * fo + g0 * fs;
            rw = rw * fo + w0 * fs;
            rm = mn;
        }
        // combine h halves
        float mo = __shfl_xor(rm, 32);
        float go = __shfl_xor(rg, 32);
        float wo = __shfl_xor(rw, 32);
        float mn = fmaxf(rm, mo);
        rg = rg * __expf((rm - mn) * rit) + go * __expf((mo - mn) * rit);
        rw = rw * __expf((rm - mn) * rit) + wo * __expf((mo - mn) * rit);
        rm = mn;
        float bloc = (rm - rd) * rit;
        if (h == 0) {
            size_t o = (size_t)blockIdx.x * BB + grow;
            pmR[o] = bloc;
            pgR[o] = rg;
            pwR[o] = rw;
        }
    }
}

// acc layout: [0]=lossI [1]=lossT [2..101]=gradI [102..201]=cntI
//             [202..301]=gradT [302..401]=cntT  [408]=completion counter(int)
// ---------------- 3) finalize: 256 blocks (2 sides x 128 chunks of 32 i) ---
// 256 threads = 32 i x 8 stripe-groups; online flash reduction per thread,
// LDS-combine across groups. 256 blocks = full CU coverage.
__global__ void __launch_bounds__(256) fin_kernel(
        const float* __restrict__ pmR, const float* __restrict__ pgR,
        const float* __restrict__ pwR, const float* __restrict__ pmC,
        const float* __restrict__ pgC, const float* __restrict__ pwC,
        const float* __restrict__ sI, const float* __restrict__ bI,
        const float* __restrict__ tausI, const int* __restrict__ gInfI,
        const float* __restrict__ pI,
        const float* __restrict__ sT, const float* __restrict__ bT,
        const float* __restrict__ tausT, const int* __restrict__ gInfT,
        const float* __restrict__ pT,
        const int* __restrict__ ids, float* __restrict__ acc,
        const float* __restrict__ zI, const float* __restrict__ zT,
        float* __restrict__ out) {
    __shared__ float lds[8];
    __shared__ float binF[GG], binC[GG];
    __shared__ float mS[8][32], gS[8][32], wS[8][32];
    __shared__ int lastFlag;
    if (threadIdx.x < GG) { binF[threadIdx.x] = 0.f; binC[threadIdx.x] = 0.f; }
    int side = blockIdx.x >> 7;
    int chunk = blockIdx.x & 127;
    int il = threadIdx.x & 31;
    int sg = threadIdx.x >> 5;
    int i = chunk * 32 + il;
    int ns = side ? NSC : NSR;
    const float* pm = side ? pmC : pmR;
    const float* pg = side ? pgC : pgR;
    const float* pw = side ? pwC : pwR;
    const float* sS = side ? sT : sI;
    const float* bS = side ? bT : bI;
    const float* taus = side ? tausT : tausI;
    const int* ginfo = side ? gInfT : gInfI;
    const float* pP = side ? pT : pI;

    // online flash over this group's stripes
    float m = -INFINITY, g = 0.f, w = 0.f;
    for (int s = sg; s < ns; s += 8) {
        float pms = pm[(size_t)s * BB + i];
        float pgs = pg[(size_t)s * BB + i];
        float pws = pw[(size_t)s * BB + i];
        float mn = fmaxf(m, pms);
        float fo = __expf(m - mn);
        float fs = __expf(pms - mn);
        g = g * fo + pgs * fs;
        w = w * fo + pws * fs;
        m = mn;
    }
    mS[sg][il] = m;
    gS[sg][il] = g;
    wS[sg][il] = w;
    __syncthreads();

    float loss = 0.f;
    if (sg == 0) {
        int id = ids[i];
        float oldb = bS[id];
        float mm = mS[0][il];
        for (int q = 1; q < 8; q++) mm = fmaxf(mm, mS[q][il]);
        float bfin = fmaxf(mm, oldb);
        float gg2 = 0.f, ww2 = 0.f;
        for (int q = 0; q < 8; q++) {
            float f = __expf(mS[q][il] - bfin);
            gg2 += gS[q][il] * f;
            ww2 += wS[q][il] * f;
        }
        float tau = taus[id];
        float snew = (1.f - GAMMA_C) * sS[id] * expf(oldb - bfin) + GAMMA_C * gg2;
        float sc = fmaxf(snew, EPS_C);
        int gid = ginfo[id];
        float gw = (float)GG * pP[gid];
        loss = gw * ww2 / sc;
        float F = tau * (logf(sc) + bfin + RHO_C);
        atomicAdd(&binF[gid], F);
        atomicAdd(&binC[gid], 1.0f);
    }
    float lsum = blockReduceSum(loss, lds);
    if (threadIdx.x == 0) atomicAdd(&acc[side], lsum);
    __syncthreads();
    if (threadIdx.x < GG) {
        atomicAdd(&acc[2 + side * 200 + threadIdx.x], binF[threadIdx.x]);
        atomicAdd(&acc[102 + side * 200 + threadIdx.x], binC[threadIdx.x]);
    }

    // ---- completion counter: last of 256 blocks runs the p-update phase ----
    __threadfence();
    if (threadIdx.x == 0) {
        int old = atomicAdd((int*)&acc[408], 1);
        lastFlag = (old == 255);
    }
    __syncthreads();
    if (!lastFlag) return;

    int gg = threadIdx.x;
    float npI = 0.f, npT = 0.f;
    if (gg < GG) {
        float cI = __hip_atomic_load(&acc[102 + gg], __ATOMIC_RELAXED, __HIP_MEMORY_SCOPE_AGENT);
        float fI = __hip_atomic_load(&acc[2 + gg], __ATOMIC_RELAXED, __HIP_MEMORY_SCOPE_AGENT);
        float gpI = fI / fmaxf(cI, 1.f);
        float zi = (1.f - GAMMA_C) * zI[gg] + GAMMA_C * gpI;
        float ghpI = -logf(pI[gg] + EPS_C) - 1.f;
        float ti = fminf(fmaxf(zi + ghpI, -5.f), 5.f);
        npI = pI[gg] * expf(0.02f * ti);

        float cT = __hip_atomic_load(&acc[302 + gg], __ATOMIC_RELAXED, __HIP_MEMORY_SCOPE_AGENT);
        float fT = __hip_atomic_load(&acc[202 + gg], __ATOMIC_RELAXED, __HIP_MEMORY_SCOPE_AGENT);
        float gpT = fT / fmaxf(cT, 1.f);
        float zt = (1.f - GAMMA_C) * zT[gg] + GAMMA_C * gpT;
        float ghpT = -logf(pT[gg] + EPS_C) - 1.f;
        float tt = fminf(fmaxf(zt + ghpT, -5.f), 5.f);
        npT = pT[gg] * expf(0.02f * tt);
    }
    float sumI = blockReduceSum(npI, lds);
    float sumT = blockReduceSum(npT, lds);
    if (gg < GG) {
        out[1 + gg] = npI / sumI;
        out[101 + gg] = npT / sumT;
    }
    if (gg == 0) {
        float lI = __hip_atomic_load(&acc[0], __ATOMIC_RELAXED, __HIP_MEMORY_SCOPE_AGENT);
        float lT = __hip_atomic_load(&acc[1], __ATOMIC_RELAXED, __HIP_MEMORY_SCOPE_AGENT);
        out[0] = ALPHA_C * (lI / (float)BB) + (1.f - ALPHA_C) * (lT / (float)BB);
    }
}

extern "C" void kernel_launch(void* const* d_in, const int* in_sizes, int n_in,
                              void* d_out, int out_size, void* d_ws, size_t ws_size,
                              hipStream_t stream) {
    const float* zis   = (const float*)d_in[0];
    const float* zjs   = (const float*)d_in[1];
    const float* s_I   = (const float*)d_in[2];
    const float* s_T   = (const float*)d_in[3];
    const float* b_I   = (const float*)d_in[4];
    const float* b_T   = (const float*)d_in[5];
    const float* z_I   = (const float*)d_in[6];
    const float* z_T   = (const float*)d_in[7];
    const float* p_I   = (const float*)d_in[8];
    const float* p_T   = (const float*)d_in[9];
    const float* tausI = (const float*)d_in[10];
    const float* tausT = (const float*)d_in[11];
    const int*   ids   = (const int*)d_in[12];
    const int*   gInfI = (const int*)d_in[13];
    const int*   gInfT = (const int*)d_in[14];
    float* out = (float*)d_out;

    char* ws = (char*)d_ws;
    ushort* zhi = (ushort*)ws;                         // BB*DD u16 each
    ushort* zlo = zhi + (size_t)BB * DD;
    ushort* whi = zlo + (size_t)BB * DD;
    ushort* wlo = whi + (size_t)BB * DD;
    float* acc  = (float*)(wlo + (size_t)BB * DD);     // 512
    float* diag = acc + 512;                           // BB
    float* pmR  = diag + BB;                           // NSR*BB each
    float* pgR  = pmR + (size_t)NSR * BB;
    float* pwR  = pgR + (size_t)NSR * BB;
    float* pmC  = pwR + (size_t)NSR * BB;              // NSC*BB each
    float* pgC  = pmC + (size_t)NSC * BB;
    float* pwC  = pgC + (size_t)NSC * BB;

    norm_kernel<<<256, 256, 0, stream>>>(zis, zjs, zhi, zlo, whi, wlo, diag, acc);
    fused_tile<<<dim3(32, 32), 256, 0, stream>>>(zhi, zlo, whi, wlo, diag,
            tausI, tausT, ids, pmR, pgR, pwR, pmC, pgC, pwC);
    fin_kernel<<<256, 256, 0, stream>>>(pmR, pgR, pwR, pmC, pgC, pwC,
            s_I, b_I, tausI, gInfI, p_I, s_T, b_T, tausT, gInfT, p_T, ids, acc,
            z_I, z_T, out);
}